// Round 2
// baseline (32743.002 us; speedup 1.0000x reference)
//
#include <hip/hip_runtime.h>
#include <hip/hip_bf16.h>
#include <hip/hip_cooperative_groups.h>

namespace cg = cooperative_groups;

#define BB 128   // batch
#define LL 512   // seq len
#define HH 2048  // hidden
#define EE 128   // embed
#define VV 96    // vocab
#define BBHH (BB * HH)

typedef short bf16x8 __attribute__((ext_vector_type(8)));
typedef float f32x4 __attribute__((ext_vector_type(4)));

__device__ __forceinline__ unsigned short f2bf(float f) {
    union { float f; unsigned int u; } c; c.f = f;
    unsigned int u = c.u;
    return (unsigned short)((u + 0x7FFFu + ((u >> 16) & 1u)) >> 16);  // RNE
}

// Persistent cooperative RNN kernel. Grid = 256 blocks = 2 bm (64 batch rows)
// x 128 bn (16 hidden cols). W_hh slice (16x2048 bf16 = 64 KB) lives in LDS in
// MFMA B-fragment-linear order -> conflict-free ds_read_b128, loaded once.
// h ping-pongs between two 512 KB global buffers; one grid.sync per step.
// Logits are computed in-kernel, pipelined one step behind, by "duty" blocks
// (bn<6, one 16-vocab tile each) reusing the recurrence A-fragments.
__global__ __launch_bounds__(256, 1)
void rnn_coop(const int* __restrict__ x, const float* __restrict__ hidden,
              const float* __restrict__ emb, const float* __restrict__ W_xh,
              const float* __restrict__ W_hh, const float* __restrict__ b_h,
              const float* __restrict__ W_hy, const float* __restrict__ b_y,
              float* __restrict__ projE, unsigned short* __restrict__ w_hy_frag,
              unsigned short* __restrict__ hbuf,
              float* __restrict__ out_logits, float* __restrict__ out_final)
{
    __shared__ __align__(16) unsigned short ldsB[4096 * 8];  // 64 KB

    const int tid  = threadIdx.x;
    const int bid  = blockIdx.x;
    const int gtid = bid * 256 + tid;   // 0..65535

    const int bm = bid >> 7;            // 0..1
    const int bn = bid & 127;           // 0..127
    const int m0 = bm * 64;
    const int n0 = bn * 16;

    // ---- LDS fill: W_hh slice -> bf16, fragment-linear (one-time) ----
    for (int c = tid; c < 4096; c += 256) {
        int i  = c >> 6;
        int l  = c & 63;
        int nl = l & 15;
        int qq = l >> 4;
        const float* src = W_hh + (size_t)(n0 + nl) * HH + (size_t)i * 32 + qq * 8;
        unsigned short tmp[8];
        #pragma unroll
        for (int j = 0; j < 8; ++j) tmp[j] = f2bf(src[j]);
        #pragma unroll
        for (int j = 0; j < 8; ++j) ldsB[c * 8 + j] = tmp[j];
    }

    // ---- projE[v][h] = b_h[h] + emb[v][:] . W_xh[h][:]  (f32, exact) ----
    for (int i = gtid; i < VV * HH; i += 65536) {
        int v  = i >> 11;
        int hc = i & (HH - 1);
        const float4* ep = (const float4*)(emb + (size_t)v * EE);
        const float4* wp = (const float4*)(W_xh + (size_t)hc * EE);
        float s = b_h[hc];
        #pragma unroll 8
        for (int e = 0; e < EE / 4; ++e) {
            float4 a = ep[e], b = wp[e];
            s += a.x * b.x + a.y * b.y + a.z * b.z + a.w * b.w;
        }
        projE[i] = s;
    }
    // ---- W_hy -> bf16, fragment-linear per 16-vocab tile ----
    // chunk c = i*64 + l of tile vt holds W_hy[vt*16 + (l&15)][i*32 + (l>>4)*8 + j]
    for (int idx = gtid; idx < VV * HH; idx += 65536) {
        int vt  = idx >> 15;            // /32768
        int rem = idx & 32767;
        int c   = rem >> 3;
        int j   = rem & 7;
        int l   = c & 63;
        int i   = c >> 6;
        int v   = vt * 16 + (l & 15);
        int k   = i * 32 + (l >> 4) * 8 + j;
        w_hy_frag[idx] = f2bf(W_hy[(size_t)v * HH + k]);
    }
    // ---- h_0 (bf16) into ping buffer 0 ----
    for (int i = gtid; i < BBHH; i += 65536) hbuf[i] = f2bf(hidden[i]);

    __syncthreads();
    cg::grid_group grid = cg::this_grid();
    __threadfence();
    grid.sync();

    const int w    = tid >> 6;      // wave 0..3 -> rows m0 + w*16
    const int lane = tid & 63;
    const int col  = lane & 15;
    const int q    = lane >> 4;
    const int am   = m0 + w * 16 + col;    // A-fragment row (batch index)
    const int n    = n0 + col;             // output hidden column
    const bf16x8* ldsB8 = (const bf16x8*)ldsB;

    const bool duty = (bn < 6);
    const int  v0   = bn * 16;             // duty vocab tile base
    const bf16x8* Hyp = (const bf16x8*)w_hy_frag + (size_t)bn * 4096 + lane;
    const float by = duty ? b_y[v0 + col] : 0.f;

    for (int t = 0; t < LL; ++t) {
        const unsigned short* hp = hbuf + (size_t)(t & 1) * BBHH;
        unsigned short* hn       = hbuf + (size_t)((t + 1) & 1) * BBHH;
        const bf16x8* Ap = (const bf16x8*)(hp + (size_t)am * HH + q * 8);

        f32x4 acc  = {0.f, 0.f, 0.f, 0.f};
        f32x4 accL = {0.f, 0.f, 0.f, 0.f};
        if (duty && t > 0) {
            #pragma unroll 4
            for (int i = 0; i < 64; ++i) {
                bf16x8 a  = Ap[i * 4];
                bf16x8 b  = ldsB8[i * 64 + lane];
                bf16x8 bl = Hyp[i * 64];
                acc  = __builtin_amdgcn_mfma_f32_16x16x32_bf16(a, b,  acc,  0, 0, 0);
                accL = __builtin_amdgcn_mfma_f32_16x16x32_bf16(a, bl, accL, 0, 0, 0);
            }
        } else {
            #pragma unroll 8
            for (int i = 0; i < 64; ++i) {
                bf16x8 a = Ap[i * 4];
                bf16x8 b = ldsB8[i * 64 + lane];
                acc = __builtin_amdgcn_mfma_f32_16x16x32_bf16(a, b, acc, 0, 0, 0);
            }
        }

        // h epilogue: C/D layout col=lane&15, row=(lane>>4)*4+r
        #pragma unroll
        for (int r = 0; r < 4; ++r) {
            int m   = m0 + w * 16 + q * 4 + r;
            int tok = x[(size_t)m * LL + t];
            float v = acc[r] + projE[(size_t)tok * HH + n];
            v = fminf(fmaxf(v, -15.f), 15.f);
            float e2 = __expf(2.f * v);
            float hv = (e2 - 1.f) / (e2 + 1.f);   // tanh
            hn[(size_t)m * HH + n] = f2bf(hv);
            if (t == LL - 1) out_final[(size_t)m * HH + n] = hv;
        }
        // logits epilogue for h_t -> position t-1
        if (duty && t > 0) {
            #pragma unroll
            for (int r = 0; r < 4; ++r) {
                int m = m0 + w * 16 + q * 4 + r;
                out_logits[(size_t)m * (LL * VV) + (size_t)(t - 1) * VV + v0 + col]
                    = accL[r] + by;
            }
        }
        __threadfence();
        grid.sync();
    }

    // logits for h_LL -> position LL-1 (read final h from ping buffer LL&1 = 0)
    if (duty) {
        const bf16x8* Ap = (const bf16x8*)(hbuf + (size_t)am * HH + q * 8);
        f32x4 accL = {0.f, 0.f, 0.f, 0.f};
        #pragma unroll 8
        for (int i = 0; i < 64; ++i) {
            bf16x8 a  = Ap[i * 4];
            bf16x8 bl = Hyp[i * 64];
            accL = __builtin_amdgcn_mfma_f32_16x16x32_bf16(a, bl, accL, 0, 0, 0);
        }
        #pragma unroll
        for (int r = 0; r < 4; ++r) {
            int m = m0 + w * 16 + q * 4 + r;
            out_logits[(size_t)m * (LL * VV) + (size_t)(LL - 1) * VV + v0 + col]
                = accL[r] + by;
        }
    }
}

extern "C" void kernel_launch(void* const* d_in, const int* in_sizes, int n_in,
                              void* d_out, int out_size, void* d_ws, size_t ws_size,
                              hipStream_t stream) {
    const int*   x      = (const int*)  d_in[0];
    const float* hidden = (const float*)d_in[1];
    const float* emb    = (const float*)d_in[2];
    const float* W_xh   = (const float*)d_in[3];
    const float* W_hh   = (const float*)d_in[4];
    const float* b_h    = (const float*)d_in[5];
    const float* W_hy   = (const float*)d_in[6];
    const float* b_y    = (const float*)d_in[7];

    float* out_logits = (float*)d_out;                          // [B][L][V]
    float* out_final  = out_logits + (size_t)BB * LL * VV;      // [B][H]

    // workspace: 768 KB projE + 384 KB w_hy_frag + 1 MB h ping-pong = ~2.2 MB
    char* ws = (char*)d_ws;
    float* projE              = (float*)ws;
    unsigned short* w_hy_frag = (unsigned short*)(ws + 786432);
    unsigned short* hbuf      = (unsigned short*)(ws + 786432 + 393216);

    void* args[] = { (void*)&x, (void*)&hidden, (void*)&emb, (void*)&W_xh,
                     (void*)&W_hh, (void*)&b_h, (void*)&W_hy, (void*)&b_y,
                     (void*)&projE, (void*)&w_hy_frag, (void*)&hbuf,
                     (void*)&out_logits, (void*)&out_final };
    hipLaunchCooperativeKernel((const void*)rnn_coop, dim3(256), dim3(256),
                               args, 0, stream);
}

// Round 3
// 15367.296 us; speedup vs baseline: 2.1307x; 2.1307x over previous
//
#include <hip/hip_runtime.h>
#include <hip/hip_bf16.h>
#include <hip/hip_cooperative_groups.h>

namespace cg = cooperative_groups;

#define BB 128   // batch
#define LL 512   // seq len
#define HH 2048  // hidden
#define EE 128   // embed
#define VV 96    // vocab
#define BBHH (BB * HH)

typedef short bf16x8 __attribute__((ext_vector_type(8)));
typedef float f32x4 __attribute__((ext_vector_type(4)));

__device__ __forceinline__ unsigned short f2bf(float f) {
    union { float f; unsigned int u; } c; c.f = f;
    unsigned int u = c.u;
    return (unsigned short)((u + 0x7FFFu + ((u >> 16) & 1u)) >> 16);  // RNE
}

// Decentralized grid barrier: no central counter (no 256-way RMW serialization),
// one L3 round-trip of depth. Block leader: release-fence (vmcnt drain +
// buffer_wbl2 sc1 -> all this XCD's dirty lines reach the coherence point),
// then agent-scope store of epoch into its own slot. Every thread polls one
// slot with sc1 loads (bypass stale per-XCD L2), s_sleep(1) between polls.
// Exit: __syncthreads (all 256 slots seen) + acquire fence (buffer_inv).
__device__ __forceinline__ void gridbar(unsigned* slots, unsigned epoch,
                                        int bid, int tid) {
    __syncthreads();  // each wave drains vmcnt before s_barrier -> h stores in L2
    if (tid == 0) {
        __builtin_amdgcn_fence(__ATOMIC_RELEASE, "agent");
        __hip_atomic_store(&slots[bid], epoch, __ATOMIC_RELAXED,
                           __HIP_MEMORY_SCOPE_AGENT);
    }
    while (__hip_atomic_load(&slots[tid], __ATOMIC_RELAXED,
                             __HIP_MEMORY_SCOPE_AGENT) < epoch) {
        __builtin_amdgcn_s_sleep(1);
    }
    __syncthreads();
    __builtin_amdgcn_fence(__ATOMIC_ACQUIRE, "agent");
}

// Persistent cooperative RNN kernel. Grid = 256 blocks = 2 bm (64 batch rows)
// x 128 bn (16 hidden cols). W_hh slice (16x2048 bf16 = 64 KB) lives in LDS in
// MFMA B-fragment-linear order -> conflict-free ds_read_b128, loaded once.
// h ping-pongs between two 512 KB global buffers; one custom barrier per step.
// Logits computed in-kernel, pipelined one step behind, by duty blocks (bn<6).
__global__ __launch_bounds__(256, 1)
void rnn_coop(const int* __restrict__ x, const float* __restrict__ hidden,
              const float* __restrict__ emb, const float* __restrict__ W_xh,
              const float* __restrict__ W_hh, const float* __restrict__ b_h,
              const float* __restrict__ W_hy, const float* __restrict__ b_y,
              float* __restrict__ projE, unsigned short* __restrict__ w_hy_frag,
              unsigned short* __restrict__ hbuf, unsigned* __restrict__ bar_slots,
              float* __restrict__ out_logits, float* __restrict__ out_final)
{
    __shared__ __align__(16) unsigned short ldsB[4096 * 8];  // 64 KB

    const int tid  = threadIdx.x;
    const int bid  = blockIdx.x;
    const int gtid = bid * 256 + tid;   // 0..65535

    const int bm = bid >> 7;            // 0..1
    const int bn = bid & 127;           // 0..127
    const int m0 = bm * 64;
    const int n0 = bn * 16;

    // ---- barrier slots = 0 (ws is poisoned 0xAA before every call) ----
    if (bid == 0) bar_slots[tid] = 0;

    // ---- LDS fill: W_hh slice -> bf16, fragment-linear (one-time) ----
    for (int c = tid; c < 4096; c += 256) {
        int i  = c >> 6;
        int l  = c & 63;
        int nl = l & 15;
        int qq = l >> 4;
        const float* src = W_hh + (size_t)(n0 + nl) * HH + (size_t)i * 32 + qq * 8;
        unsigned short tmp[8];
        #pragma unroll
        for (int j = 0; j < 8; ++j) tmp[j] = f2bf(src[j]);
        #pragma unroll
        for (int j = 0; j < 8; ++j) ldsB[c * 8 + j] = tmp[j];
    }

    // ---- projE[v][h] = b_h[h] + emb[v][:] . W_xh[h][:]  (f32, exact) ----
    for (int i = gtid; i < VV * HH; i += 65536) {
        int v  = i >> 11;
        int hc = i & (HH - 1);
        const float4* ep = (const float4*)(emb + (size_t)v * EE);
        const float4* wp = (const float4*)(W_xh + (size_t)hc * EE);
        float s = b_h[hc];
        #pragma unroll 8
        for (int e = 0; e < EE / 4; ++e) {
            float4 a = ep[e], b = wp[e];
            s += a.x * b.x + a.y * b.y + a.z * b.z + a.w * b.w;
        }
        projE[i] = s;
    }
    // ---- W_hy -> bf16, fragment-linear per 16-vocab tile ----
    for (int idx = gtid; idx < VV * HH; idx += 65536) {
        int vt  = idx >> 15;            // /32768
        int rem = idx & 32767;
        int c   = rem >> 3;
        int j   = rem & 7;
        int l   = c & 63;
        int i   = c >> 6;
        int v   = vt * 16 + (l & 15);
        int k   = i * 32 + (l >> 4) * 8 + j;
        w_hy_frag[idx] = f2bf(W_hy[(size_t)v * HH + k]);
    }
    // ---- h_0 (bf16) into ping buffer 0 ----
    for (int i = gtid; i < BBHH; i += 65536) hbuf[i] = f2bf(hidden[i]);

    __syncthreads();
    cg::grid_group grid = cg::this_grid();
    __threadfence();
    grid.sync();   // one-time full sync: publishes setup writes + zeroed slots

    const int w    = tid >> 6;      // wave 0..3 -> rows m0 + w*16
    const int lane = tid & 63;
    const int col  = lane & 15;
    const int q    = lane >> 4;
    const int am   = m0 + w * 16 + col;    // A-fragment row (batch index)
    const int n    = n0 + col;             // output hidden column
    const bf16x8* ldsB8 = (const bf16x8*)ldsB;

    const bool duty = (bn < 6);
    const int  v0   = bn * 16;             // duty vocab tile base
    const bf16x8* Hyp = (const bf16x8*)w_hy_frag + (size_t)bn * 4096 + lane;
    const float by = duty ? b_y[v0 + col] : 0.f;

    for (int t = 0; t < LL; ++t) {
        const unsigned short* hp = hbuf + (size_t)(t & 1) * BBHH;
        unsigned short* hn       = hbuf + (size_t)((t + 1) & 1) * BBHH;
        const bf16x8* Ap = (const bf16x8*)(hp + (size_t)am * HH + q * 8);

        f32x4 acc  = {0.f, 0.f, 0.f, 0.f};
        f32x4 accL = {0.f, 0.f, 0.f, 0.f};
        if (duty && t > 0) {
            #pragma unroll 4
            for (int i = 0; i < 64; ++i) {
                bf16x8 a  = Ap[i * 4];
                bf16x8 b  = ldsB8[i * 64 + lane];
                bf16x8 bl = Hyp[i * 64];
                acc  = __builtin_amdgcn_mfma_f32_16x16x32_bf16(a, b,  acc,  0, 0, 0);
                accL = __builtin_amdgcn_mfma_f32_16x16x32_bf16(a, bl, accL, 0, 0, 0);
            }
        } else {
            #pragma unroll 8
            for (int i = 0; i < 64; ++i) {
                bf16x8 a = Ap[i * 4];
                bf16x8 b = ldsB8[i * 64 + lane];
                acc = __builtin_amdgcn_mfma_f32_16x16x32_bf16(a, b, acc, 0, 0, 0);
            }
        }

        // h epilogue: C/D layout col=lane&15, row=(lane>>4)*4+r
        #pragma unroll
        for (int r = 0; r < 4; ++r) {
            int m   = m0 + w * 16 + q * 4 + r;
            int tok = x[(size_t)m * LL + t];
            float v = acc[r] + projE[(size_t)tok * HH + n];
            v = fminf(fmaxf(v, -15.f), 15.f);
            float e2 = __expf(2.f * v);
            float hv = (e2 - 1.f) / (e2 + 1.f);   // tanh
            hn[(size_t)m * HH + n] = f2bf(hv);
            if (t == LL - 1) out_final[(size_t)m * HH + n] = hv;
        }
        // logits epilogue for h_t -> position t-1
        if (duty && t > 0) {
            #pragma unroll
            for (int r = 0; r < 4; ++r) {
                int m = m0 + w * 16 + q * 4 + r;
                out_logits[(size_t)m * (LL * VV) + (size_t)(t - 1) * VV + v0 + col]
                    = accL[r] + by;
            }
        }
        gridbar(bar_slots, (unsigned)(t + 1), bid, tid);
    }

    // logits for h_LL -> position LL-1 (final h is in ping buffer LL&1 = 0)
    if (duty) {
        const bf16x8* Ap = (const bf16x8*)(hbuf + (size_t)am * HH + q * 8);
        f32x4 accL = {0.f, 0.f, 0.f, 0.f};
        #pragma unroll 8
        for (int i = 0; i < 64; ++i) {
            bf16x8 a  = Ap[i * 4];
            bf16x8 bl = Hyp[i * 64];
            accL = __builtin_amdgcn_mfma_f32_16x16x32_bf16(a, bl, accL, 0, 0, 0);
        }
        #pragma unroll
        for (int r = 0; r < 4; ++r) {
            int m = m0 + w * 16 + q * 4 + r;
            out_logits[(size_t)m * (LL * VV) + (size_t)(LL - 1) * VV + v0 + col]
                = accL[r] + by;
        }
    }
}

extern "C" void kernel_launch(void* const* d_in, const int* in_sizes, int n_in,
                              void* d_out, int out_size, void* d_ws, size_t ws_size,
                              hipStream_t stream) {
    const int*   x      = (const int*)  d_in[0];
    const float* hidden = (const float*)d_in[1];
    const float* emb    = (const float*)d_in[2];
    const float* W_xh   = (const float*)d_in[3];
    const float* W_hh   = (const float*)d_in[4];
    const float* b_h    = (const float*)d_in[5];
    const float* W_hy   = (const float*)d_in[6];
    const float* b_y    = (const float*)d_in[7];

    float* out_logits = (float*)d_out;                          // [B][L][V]
    float* out_final  = out_logits + (size_t)BB * LL * VV;      // [B][H]

    // workspace: 768 KB projE + 384 KB w_hy_frag + 1 MB h ping-pong + slots
    char* ws = (char*)d_ws;
    float* projE              = (float*)ws;
    unsigned short* w_hy_frag = (unsigned short*)(ws + 786432);
    unsigned short* hbuf      = (unsigned short*)(ws + 786432 + 393216);
    unsigned* bar_slots       = (unsigned*)(ws + 786432 + 393216 + 2 * BBHH * 2);

    void* args[] = { (void*)&x, (void*)&hidden, (void*)&emb, (void*)&W_xh,
                     (void*)&W_hh, (void*)&b_h, (void*)&W_hy, (void*)&b_y,
                     (void*)&projE, (void*)&w_hy_frag, (void*)&hbuf,
                     (void*)&bar_slots, (void*)&out_logits, (void*)&out_final };
    hipLaunchCooperativeKernel((const void*)rnn_coop, dim3(256), dim3(256),
                               args, 0, stream);
}

// Round 4
// 11134.138 us; speedup vs baseline: 2.9408x; 1.3802x over previous
//
#include <hip/hip_runtime.h>
#include <hip/hip_bf16.h>
#include <hip/hip_cooperative_groups.h>

namespace cg = cooperative_groups;

#define BB 128   // batch
#define LL 512   // seq len
#define HH 2048  // hidden
#define EE 128   // embed
#define VV 96    // vocab
#define BBHH (BB * HH)
#define NBLK 256

typedef short bf16x8 __attribute__((ext_vector_type(8)));
typedef float f32x4 __attribute__((ext_vector_type(4)));

__device__ __forceinline__ unsigned short f2bf(float f) {
    union { float f; unsigned int u; } c; c.f = f;
    unsigned int u = c.u;
    return (unsigned short)((u + 0x7FFFu + ((u >> 16) & 1u)) >> 16);  // RNE
}

__device__ __forceinline__ unsigned long long ld_dev(const unsigned long long* p) {
    return __hip_atomic_load(p, __ATOMIC_RELAXED, __HIP_MEMORY_SCOPE_AGENT);
}
__device__ __forceinline__ void st_dev(unsigned short* p, unsigned short v) {
    __hip_atomic_store(p, v, __ATOMIC_RELAXED, __HIP_MEMORY_SCOPE_AGENT);
}

// Fence-free grid barrier. All mutable cross-block data (h, barrier words) is
// accessed with device-scope (sc1) ops that bypass the non-coherent per-XCD
// L2s, so NO buffer_wbl2/buffer_inv cache walks are needed. Ordering:
// __syncthreads drains each wave's vmcnt (sc1 stores acked at the coherence
// point), explicit s_waitcnt pins the arrival add after the drain. Only tid 0
// arrives+polls; the rest wait at s_barrier.
__device__ __forceinline__ void gridbar(unsigned* counter, unsigned* flag,
                                        unsigned epoch, int tid) {
    __syncthreads();   // compiler emits s_waitcnt vmcnt(0) lgkmcnt(0) + s_barrier
    if (tid == 0) {
        asm volatile("s_waitcnt vmcnt(0)" ::: "memory");
        unsigned old = __hip_atomic_fetch_add(counter, 1u, __ATOMIC_RELAXED,
                                              __HIP_MEMORY_SCOPE_AGENT);
        if (old == epoch * NBLK - 1) {
            __hip_atomic_store(flag, epoch, __ATOMIC_RELAXED,
                               __HIP_MEMORY_SCOPE_AGENT);
        } else {
            while (__hip_atomic_load(flag, __ATOMIC_RELAXED,
                                     __HIP_MEMORY_SCOPE_AGENT) < epoch)
                __builtin_amdgcn_s_sleep(1);
        }
    }
    __syncthreads();
}

// Persistent cooperative RNN kernel. Grid = 256 blocks = 2 bm (64 batch rows)
// x 128 bn (16 hidden cols). W_hh slice (16x2048 bf16 = 64 KB) in LDS in MFMA
// B-fragment-linear order, loaded once. h ping-pongs between two 512 KB global
// buffers, written/read with device-scope (sc1) ops; one fence-free barrier
// per step. Logits computed in-kernel, one step behind, by duty blocks (bn<6).
__global__ __launch_bounds__(256, 1)
void rnn_coop(const int* __restrict__ x, const float* __restrict__ hidden,
              const float* __restrict__ emb, const float* __restrict__ W_xh,
              const float* __restrict__ W_hh, const float* __restrict__ b_h,
              const float* __restrict__ W_hy, const float* __restrict__ b_y,
              float* __restrict__ projE, unsigned short* __restrict__ w_hy_frag,
              unsigned short* __restrict__ hbuf, unsigned* __restrict__ bar,
              float* __restrict__ out_logits, float* __restrict__ out_final)
{
    __shared__ __align__(16) unsigned short ldsB[4096 * 8];  // 64 KB

    const int tid  = threadIdx.x;
    const int bid  = blockIdx.x;
    const int gtid = bid * 256 + tid;   // 0..65535

    const int bm = bid >> 7;            // 0..1
    const int bn = bid & 127;           // 0..127
    const int m0 = bm * 64;
    const int n0 = bn * 16;

    unsigned* bar_counter = bar;        // one line
    unsigned* bar_flag    = bar + 64;   // separate line

    // ---- barrier words = 0 (ws is re-poisoned 0xAA before every call) ----
    if (bid == 0 && tid < 128) bar[tid] = 0;

    // ---- LDS fill: W_hh slice -> bf16, fragment-linear (one-time) ----
    for (int c = tid; c < 4096; c += 256) {
        int i  = c >> 6;
        int l  = c & 63;
        int nl = l & 15;
        int qq = l >> 4;
        const float* src = W_hh + (size_t)(n0 + nl) * HH + (size_t)i * 32 + qq * 8;
        unsigned short tmp[8];
        #pragma unroll
        for (int j = 0; j < 8; ++j) tmp[j] = f2bf(src[j]);
        #pragma unroll
        for (int j = 0; j < 8; ++j) ldsB[c * 8 + j] = tmp[j];
    }

    // ---- projE[v][h] = b_h[h] + emb[v][:] . W_xh[h][:]  (f32, exact) ----
    for (int i = gtid; i < VV * HH; i += 65536) {
        int v  = i >> 11;
        int hc = i & (HH - 1);
        const float4* ep = (const float4*)(emb + (size_t)v * EE);
        const float4* wp = (const float4*)(W_xh + (size_t)hc * EE);
        float s = b_h[hc];
        #pragma unroll 8
        for (int e = 0; e < EE / 4; ++e) {
            float4 a = ep[e], b = wp[e];
            s += a.x * b.x + a.y * b.y + a.z * b.z + a.w * b.w;
        }
        projE[i] = s;
    }
    // ---- W_hy -> bf16, fragment-linear per 16-vocab tile ----
    for (int idx = gtid; idx < VV * HH; idx += 65536) {
        int vt  = idx >> 15;            // /32768
        int rem = idx & 32767;
        int c   = rem >> 3;
        int j   = rem & 7;
        int l   = c & 63;
        int i   = c >> 6;
        int v   = vt * 16 + (l & 15);
        int k   = i * 32 + (l >> 4) * 8 + j;
        w_hy_frag[idx] = f2bf(W_hy[(size_t)v * HH + k]);
    }
    // ---- h_0 (bf16) into ping buffer 0 ----
    for (int i = gtid; i < BBHH; i += 65536) hbuf[i] = f2bf(hidden[i]);

    __syncthreads();
    cg::grid_group grid = cg::this_grid();
    __threadfence();
    grid.sync();   // one-time: publishes setup writes (incl. zeroed bar words)

    const int w    = tid >> 6;      // wave 0..3 -> rows m0 + w*16
    const int lane = tid & 63;
    const int col  = lane & 15;
    const int q    = lane >> 4;
    const int am   = m0 + w * 16 + col;    // A-fragment row (batch index)
    const int n    = n0 + col;             // output hidden column
    const bf16x8* ldsB8 = (const bf16x8*)ldsB;

    const bool duty = (bn < 6);
    const int  v0   = bn * 16;             // duty vocab tile base
    const bf16x8* Hyp = (const bf16x8*)w_hy_frag + (size_t)bn * 4096 + lane;
    const float by = duty ? b_y[v0 + col] : 0.f;

    for (int t = 0; t < LL; ++t) {
        const unsigned short* hp = hbuf + (size_t)(t & 1) * BBHH;
        unsigned short* hn       = hbuf + (size_t)((t + 1) & 1) * BBHH;
        const unsigned long long* Ap8 =
            (const unsigned long long*)(hp + (size_t)am * HH) + q * 2;

        f32x4 acc  = {0.f, 0.f, 0.f, 0.f};
        f32x4 accL = {0.f, 0.f, 0.f, 0.f};
        if (duty && t > 0) {
            #pragma unroll 4
            for (int i = 0; i < 64; ++i) {
                union { unsigned long long u[2]; bf16x8 v; } A;
                A.u[0] = ld_dev(Ap8 + (size_t)i * 8);
                A.u[1] = ld_dev(Ap8 + (size_t)i * 8 + 1);
                bf16x8 b  = ldsB8[i * 64 + lane];
                bf16x8 bl = Hyp[i * 64];
                acc  = __builtin_amdgcn_mfma_f32_16x16x32_bf16(A.v, b,  acc,  0, 0, 0);
                accL = __builtin_amdgcn_mfma_f32_16x16x32_bf16(A.v, bl, accL, 0, 0, 0);
            }
        } else {
            #pragma unroll 8
            for (int i = 0; i < 64; ++i) {
                union { unsigned long long u[2]; bf16x8 v; } A;
                A.u[0] = ld_dev(Ap8 + (size_t)i * 8);
                A.u[1] = ld_dev(Ap8 + (size_t)i * 8 + 1);
                bf16x8 b = ldsB8[i * 64 + lane];
                acc = __builtin_amdgcn_mfma_f32_16x16x32_bf16(A.v, b, acc, 0, 0, 0);
            }
        }

        // h epilogue: C/D layout col=lane&15, row=(lane>>4)*4+r
        #pragma unroll
        for (int r = 0; r < 4; ++r) {
            int m   = m0 + w * 16 + q * 4 + r;
            int tok = x[(size_t)m * LL + t];
            float v = acc[r] + projE[(size_t)tok * HH + n];
            v = fminf(fmaxf(v, -15.f), 15.f);
            float e2 = __expf(2.f * v);
            float hv = (e2 - 1.f) / (e2 + 1.f);   // tanh
            st_dev(&hn[(size_t)m * HH + n], f2bf(hv));
            if (t == LL - 1) out_final[(size_t)m * HH + n] = hv;
        }
        // logits epilogue for h_t -> position t-1
        if (duty && t > 0) {
            #pragma unroll
            for (int r = 0; r < 4; ++r) {
                int m = m0 + w * 16 + q * 4 + r;
                out_logits[(size_t)m * (LL * VV) + (size_t)(t - 1) * VV + v0 + col]
                    = accL[r] + by;
            }
        }
        gridbar(bar_counter, bar_flag, (unsigned)(t + 1), tid);
    }

    // logits for h_LL -> position LL-1 (final h is in ping buffer LL&1 = 0)
    if (duty) {
        const unsigned long long* Ap8 =
            (const unsigned long long*)(hbuf + (size_t)am * HH) + q * 2;
        f32x4 accL = {0.f, 0.f, 0.f, 0.f};
        #pragma unroll 8
        for (int i = 0; i < 64; ++i) {
            union { unsigned long long u[2]; bf16x8 v; } A;
            A.u[0] = ld_dev(Ap8 + (size_t)i * 8);
            A.u[1] = ld_dev(Ap8 + (size_t)i * 8 + 1);
            bf16x8 bl = Hyp[i * 64];
            accL = __builtin_amdgcn_mfma_f32_16x16x32_bf16(A.v, bl, accL, 0, 0, 0);
        }
        #pragma unroll
        for (int r = 0; r < 4; ++r) {
            int m = m0 + w * 16 + q * 4 + r;
            out_logits[(size_t)m * (LL * VV) + (size_t)(LL - 1) * VV + v0 + col]
                = accL[r] + by;
        }
    }
}

extern "C" void kernel_launch(void* const* d_in, const int* in_sizes, int n_in,
                              void* d_out, int out_size, void* d_ws, size_t ws_size,
                              hipStream_t stream) {
    const int*   x      = (const int*)  d_in[0];
    const float* hidden = (const float*)d_in[1];
    const float* emb    = (const float*)d_in[2];
    const float* W_xh   = (const float*)d_in[3];
    const float* W_hh   = (const float*)d_in[4];
    const float* b_h    = (const float*)d_in[5];
    const float* W_hy   = (const float*)d_in[6];
    const float* b_y    = (const float*)d_in[7];

    float* out_logits = (float*)d_out;                          // [B][L][V]
    float* out_final  = out_logits + (size_t)BB * LL * VV;      // [B][H]

    // workspace: 768 KB projE + 384 KB w_hy_frag + 1 MB h ping-pong + barrier
    char* ws = (char*)d_ws;
    float* projE              = (float*)ws;
    unsigned short* w_hy_frag = (unsigned short*)(ws + 786432);
    unsigned short* hbuf      = (unsigned short*)(ws + 786432 + 393216);
    unsigned* bar             = (unsigned*)(ws + 786432 + 393216 + 2 * BBHH * 2);

    void* args[] = { (void*)&x, (void*)&hidden, (void*)&emb, (void*)&W_xh,
                     (void*)&W_hh, (void*)&b_h, (void*)&W_hy, (void*)&b_y,
                     (void*)&projE, (void*)&w_hy_frag, (void*)&hbuf,
                     (void*)&bar, (void*)&out_logits, (void*)&out_final };
    hipLaunchCooperativeKernel((const void*)rnn_coop, dim3(256), dim3(256),
                               args, 0, stream);
}

// Round 5
// 10477.608 us; speedup vs baseline: 3.1250x; 1.0627x over previous
//
#include <hip/hip_runtime.h>
#include <hip/hip_bf16.h>
#include <hip/hip_cooperative_groups.h>

namespace cg = cooperative_groups;

#define BB 128   // batch
#define LL 512   // seq len
#define HH 2048  // hidden
#define EE 128   // embed
#define VV 96    // vocab
#define BBHH (BB * HH)
#define NBLK 256

typedef short bf16x8 __attribute__((ext_vector_type(8)));
typedef float f32x4 __attribute__((ext_vector_type(4)));

__device__ __forceinline__ unsigned short f2bf(float f) {
    union { float f; unsigned int u; } c; c.f = f;
    unsigned int u = c.u;
    return (unsigned short)((u + 0x7FFFu + ((u >> 16) & 1u)) >> 16);  // RNE
}

__device__ __forceinline__ unsigned long long ld_dev(const unsigned long long* p) {
    return __hip_atomic_load(p, __ATOMIC_RELAXED, __HIP_MEMORY_SCOPE_AGENT);
}
__device__ __forceinline__ void st_dev(unsigned short* p, unsigned short v) {
    __hip_atomic_store(p, v, __ATOMIC_RELAXED, __HIP_MEMORY_SCOPE_AGENT);
}

// Fence-free grid barrier; device-scope (sc1) ops bypass the non-coherent
// per-XCD L2s for the barrier words, so no cache walks. tid 0 drains vmcnt
// (all sc1 h-stores acked at coherence point) then arrives on the central
// counter; all of wave 0 BUSY-SPINS on the flag (no s_sleep: keeps the CU's
// issue rate up so the SMU doesn't downclock, and detects the flag within one
// fabric round trip). Other waves wait at s_barrier.
__device__ __forceinline__ void gridbar(unsigned* counter, unsigned* flag,
                                        unsigned epoch, int tid) {
    __syncthreads();   // s_waitcnt vmcnt(0) lgkmcnt(0) + s_barrier
    if (tid == 0) {
        asm volatile("s_waitcnt vmcnt(0)" ::: "memory");
        unsigned old = __hip_atomic_fetch_add(counter, 1u, __ATOMIC_RELAXED,
                                              __HIP_MEMORY_SCOPE_AGENT);
        if (old == epoch * NBLK - 1)
            __hip_atomic_store(flag, epoch, __ATOMIC_RELAXED,
                               __HIP_MEMORY_SCOPE_AGENT);
    }
    if (tid < 64) {
        while (__hip_atomic_load(flag, __ATOMIC_RELAXED,
                                 __HIP_MEMORY_SCOPE_AGENT) < epoch) {
            // busy spin
        }
    }
    __syncthreads();
}

// Persistent cooperative RNN kernel. Grid = 256 blocks = 2 bm (64 batch rows)
// x 128 bn (16 hidden cols). W_hh slice (16x2048 bf16 = 64 KB) in LDS in MFMA
// B-fragment-linear order, loaded once. h ping-pongs between two 512 KB global
// buffers, written/read with device-scope (sc1) ops; one fence-free barrier
// per step. Logits computed in-kernel, one step behind, by duty blocks (bn<6).
// Next-step tokens + projE values are prefetched before the barrier so their
// latency hides behind the store drain / flag wait.
__global__ __launch_bounds__(256, 1)
void rnn_coop(const int* __restrict__ x, const float* __restrict__ hidden,
              const float* __restrict__ emb, const float* __restrict__ W_xh,
              const float* __restrict__ W_hh, const float* __restrict__ b_h,
              const float* __restrict__ W_hy, const float* __restrict__ b_y,
              float* __restrict__ projE, unsigned short* __restrict__ w_hy_frag,
              unsigned short* __restrict__ hbuf, unsigned* __restrict__ bar,
              float* __restrict__ out_logits, float* __restrict__ out_final)
{
    __shared__ __align__(16) unsigned short ldsB[4096 * 8];  // 64 KB

    const int tid  = threadIdx.x;
    const int bid  = blockIdx.x;
    const int gtid = bid * 256 + tid;   // 0..65535

    const int bm = bid >> 7;            // 0..1
    const int bn = bid & 127;           // 0..127
    const int m0 = bm * 64;
    const int n0 = bn * 16;

    unsigned* bar_counter = bar;        // one line
    unsigned* bar_flag    = bar + 64;   // separate line

    // ---- barrier words = 0 (ws is re-poisoned 0xAA before every call) ----
    if (bid == 0 && tid < 128) bar[tid] = 0;

    // ---- LDS fill: W_hh slice -> bf16, fragment-linear (one-time) ----
    for (int c = tid; c < 4096; c += 256) {
        int i  = c >> 6;
        int l  = c & 63;
        int nl = l & 15;
        int qq = l >> 4;
        const float* src = W_hh + (size_t)(n0 + nl) * HH + (size_t)i * 32 + qq * 8;
        unsigned short tmp[8];
        #pragma unroll
        for (int j = 0; j < 8; ++j) tmp[j] = f2bf(src[j]);
        #pragma unroll
        for (int j = 0; j < 8; ++j) ldsB[c * 8 + j] = tmp[j];
    }

    // ---- projE[v][h] = b_h[h] + emb[v][:] . W_xh[h][:]  (f32, exact) ----
    for (int i = gtid; i < VV * HH; i += 65536) {
        int v  = i >> 11;
        int hc = i & (HH - 1);
        const float4* ep = (const float4*)(emb + (size_t)v * EE);
        const float4* wp = (const float4*)(W_xh + (size_t)hc * EE);
        float s = b_h[hc];
        #pragma unroll 8
        for (int e = 0; e < EE / 4; ++e) {
            float4 a = ep[e], b = wp[e];
            s += a.x * b.x + a.y * b.y + a.z * b.z + a.w * b.w;
        }
        projE[i] = s;
    }
    // ---- W_hy -> bf16, fragment-linear per 16-vocab tile ----
    for (int idx = gtid; idx < VV * HH; idx += 65536) {
        int vt  = idx >> 15;            // /32768
        int rem = idx & 32767;
        int c   = rem >> 3;
        int j   = rem & 7;
        int l   = c & 63;
        int i   = c >> 6;
        int v   = vt * 16 + (l & 15);
        int k   = i * 32 + (l >> 4) * 8 + j;
        w_hy_frag[idx] = f2bf(W_hy[(size_t)v * HH + k]);
    }
    // ---- h_0 (bf16) into ping buffer 0 ----
    for (int i = gtid; i < BBHH; i += 65536) hbuf[i] = f2bf(hidden[i]);

    __syncthreads();
    cg::grid_group grid = cg::this_grid();
    __threadfence();
    grid.sync();   // one-time: publishes setup writes (incl. zeroed bar words)

    const int w    = tid >> 6;      // wave 0..3 -> rows m0 + w*16
    const int lane = tid & 63;
    const int col  = lane & 15;
    const int q    = lane >> 4;
    const int am   = m0 + w * 16 + col;    // A-fragment row (batch index)
    const int n    = n0 + col;             // output hidden column
    const bf16x8* ldsB8 = (const bf16x8*)ldsB;

    const bool duty = (bn < 6);
    const int  v0   = bn * 16;             // duty vocab tile base
    const bf16x8* Hyp = (const bf16x8*)w_hy_frag + (size_t)bn * 4096 + lane;
    const float by = duty ? b_y[v0 + col] : 0.f;

    // per-thread epilogue rows + first-step prefetch of projE values
    int   mrow[4];
    float pv[4];
    #pragma unroll
    for (int r = 0; r < 4; ++r) {
        mrow[r] = m0 + w * 16 + q * 4 + r;
        int tok = x[(size_t)mrow[r] * LL];
        pv[r]   = projE[(size_t)tok * HH + n];
    }

    for (int t = 0; t < LL; ++t) {
        const unsigned short* hp = hbuf + (size_t)(t & 1) * BBHH;
        unsigned short* hn       = hbuf + (size_t)((t + 1) & 1) * BBHH;
        const unsigned long long* Ap8 =
            (const unsigned long long*)(hp + (size_t)am * HH) + q * 2;

        f32x4 acc  = {0.f, 0.f, 0.f, 0.f};
        f32x4 accL = {0.f, 0.f, 0.f, 0.f};
        if (duty && t > 0) {
            #pragma unroll 4
            for (int i = 0; i < 64; ++i) {
                union { unsigned long long u[2]; bf16x8 v; } A;
                A.u[0] = ld_dev(Ap8 + (size_t)i * 8);
                A.u[1] = ld_dev(Ap8 + (size_t)i * 8 + 1);
                bf16x8 b  = ldsB8[i * 64 + lane];
                bf16x8 bl = Hyp[i * 64];
                acc  = __builtin_amdgcn_mfma_f32_16x16x32_bf16(A.v, b,  acc,  0, 0, 0);
                accL = __builtin_amdgcn_mfma_f32_16x16x32_bf16(A.v, bl, accL, 0, 0, 0);
            }
        } else {
            #pragma unroll 8
            for (int i = 0; i < 64; ++i) {
                union { unsigned long long u[2]; bf16x8 v; } A;
                A.u[0] = ld_dev(Ap8 + (size_t)i * 8);
                A.u[1] = ld_dev(Ap8 + (size_t)i * 8 + 1);
                bf16x8 b = ldsB8[i * 64 + lane];
                acc = __builtin_amdgcn_mfma_f32_16x16x32_bf16(A.v, b, acc, 0, 0, 0);
            }
        }

        // h epilogue: C/D layout col=lane&15, row=(lane>>4)*4+r
        #pragma unroll
        for (int r = 0; r < 4; ++r) {
            float v = acc[r] + pv[r];
            v = fminf(fmaxf(v, -15.f), 15.f);
            float e2 = __expf(2.f * v);
            float hv = (e2 - 1.f) / (e2 + 1.f);   // tanh
            st_dev(&hn[(size_t)mrow[r] * HH + n], f2bf(hv));
            if (t == LL - 1) out_final[(size_t)mrow[r] * HH + n] = hv;
        }
        // logits epilogue for h_t -> position t-1
        if (duty && t > 0) {
            #pragma unroll
            for (int r = 0; r < 4; ++r) {
                out_logits[(size_t)mrow[r] * (LL * VV) + (size_t)(t - 1) * VV + v0 + col]
                    = accL[r] + by;
            }
        }
        // prefetch next step's projE values (cached loads; latency hides
        // behind the barrier's store drain + flag wait)
        if (t + 1 < LL) {
            #pragma unroll
            for (int r = 0; r < 4; ++r) {
                int tok = x[(size_t)mrow[r] * LL + t + 1];
                pv[r]   = projE[(size_t)tok * HH + n];
            }
        }
        gridbar(bar_counter, bar_flag, (unsigned)(t + 1), tid);
    }

    // logits for h_LL -> position LL-1 (final h is in ping buffer LL&1 = 0)
    if (duty) {
        const unsigned long long* Ap8 =
            (const unsigned long long*)(hbuf + (size_t)am * HH) + q * 2;
        f32x4 accL = {0.f, 0.f, 0.f, 0.f};
        #pragma unroll 8
        for (int i = 0; i < 64; ++i) {
            union { unsigned long long u[2]; bf16x8 v; } A;
            A.u[0] = ld_dev(Ap8 + (size_t)i * 8);
            A.u[1] = ld_dev(Ap8 + (size_t)i * 8 + 1);
            bf16x8 bl = Hyp[i * 64];
            accL = __builtin_amdgcn_mfma_f32_16x16x32_bf16(A.v, bl, accL, 0, 0, 0);
        }
        #pragma unroll
        for (int r = 0; r < 4; ++r) {
            int m = m0 + w * 16 + q * 4 + r;
            out_logits[(size_t)m * (LL * VV) + (size_t)(LL - 1) * VV + v0 + col]
                = accL[r] + by;
        }
    }
}

extern "C" void kernel_launch(void* const* d_in, const int* in_sizes, int n_in,
                              void* d_out, int out_size, void* d_ws, size_t ws_size,
                              hipStream_t stream) {
    const int*   x      = (const int*)  d_in[0];
    const float* hidden = (const float*)d_in[1];
    const float* emb    = (const float*)d_in[2];
    const float* W_xh   = (const float*)d_in[3];
    const float* W_hh   = (const float*)d_in[4];
    const float* b_h    = (const float*)d_in[5];
    const float* W_hy   = (const float*)d_in[6];
    const float* b_y    = (const float*)d_in[7];

    float* out_logits = (float*)d_out;                          // [B][L][V]
    float* out_final  = out_logits + (size_t)BB * LL * VV;      // [B][H]

    // workspace: 768 KB projE + 384 KB w_hy_frag + 1 MB h ping-pong + barrier
    char* ws = (char*)d_ws;
    float* projE              = (float*)ws;
    unsigned short* w_hy_frag = (unsigned short*)(ws + 786432);
    unsigned short* hbuf      = (unsigned short*)(ws + 786432 + 393216);
    unsigned* bar             = (unsigned*)(ws + 786432 + 393216 + 2 * BBHH * 2);

    void* args[] = { (void*)&x, (void*)&hidden, (void*)&emb, (void*)&W_xh,
                     (void*)&W_hh, (void*)&b_h, (void*)&W_hy, (void*)&b_y,
                     (void*)&projE, (void*)&w_hy_frag, (void*)&hbuf,
                     (void*)&bar, (void*)&out_logits, (void*)&out_final };
    hipLaunchCooperativeKernel((const void*)rnn_coop, dim3(256), dim3(256),
                               args, 0, stream);
}